// Round 10
// baseline (276.526 us; speedup 1.0000x reference)
//
#include <hip/hip_runtime.h>
#include <hip/hip_bf16.h>
#include <math.h>

typedef unsigned short u16;
typedef __attribute__((ext_vector_type(8))) short short8;
typedef __attribute__((ext_vector_type(4))) float f32x4;
typedef __attribute__((ext_vector_type(4))) unsigned short u16x4;

#define DEVINL static __device__ __forceinline__

DEVINL float b2f(u16 x) {
    union { unsigned u; float f; } v; v.u = ((unsigned)x) << 16; return v.f;
}
DEVINL u16 f2b(float f) {
    union { unsigned u; float f; } v; v.f = f;
    unsigned u = v.u;
    return (u16)((u + 0x7fffu + ((u >> 16) & 1u)) >> 16);
}
DEVINL float silu(float x) { return x / (1.f + __expf(-x)); }
DEVINL float ld_any(bool f32, const void* p, size_t i) {
    return f32 ? ((const float*)p)[i] : b2f(((const u16*)p)[i]);
}
template<bool F32> DEVINL float LDs(const void* p, size_t i) {
    if constexpr (F32) return ((const float*)p)[i];
    else               return b2f(((const u16*)p)[i]);
}

// Inline dtype detect: sample the 64 EVEN u16s of resnet. f32 input -> even
// u16s are mantissa halves (~46% trigger each, P[none]~4e-18); bf16 -> 0.
DEVINL bool detect_f32(const u16* __restrict__ raw) {
    int cnt = 0;
#pragma unroll
    for (int i = 0; i < 64; ++i) {
        float v = b2f(raw[i * 2]);
        if (!(fabsf(v) <= 1e3f)) cnt++;
    }
    return cnt > 0;
}

// --- converted-weights arena: element offsets inside w16 (bf16) ---
#define O_INW  0        /* 1024*256 */
#define O_XPW  262144   /* 48*512 */
#define O_OPW  286720   /* 256*512 */
#define O_SPW  417792   /* 256*512 */
#define O_CW   548864   /* 512*3 */
#define O_CB   550400   /* 512 */
#define O_DTW  550912   /* 512*16 */
#define O_ALOG 559104   /* 512*16 */
#define O_DTB  567296   /* 512 */
#define O_DW   567808   /* 512 */
#define O_SG   568320
#define O_SB   568576
#define O_SM   568832
#define O_SV   569088
#define O_RG   569344
#define O_RB   569600
#define O_RM   569856
#define O_RV   570112
#define O_LG   570368
#define O_LB   570624
#define N_CVT  570880

// ---------------------------------------------------------------------------
// k_prep: weight/param cvt (blocks 0..2229) + scp transpose (2230..2485)
// + resnet transpose (2486..2997). Self-detects dtype.
// ---------------------------------------------------------------------------
DEVINL void tr_tile(bool f32, const void* src, u16* dst, int R, int C,
                    int c0, int r0, int b, int tid)
{
    __shared__ u16 t[64][66];
    int lane = tid & 63, grp = tid >> 6;
#pragma unroll
    for (int j = 0; j < 16; ++j) {
        int rl = j * 4 + grp;
        t[rl][lane] = f2b(ld_any(f32, src, ((size_t)b * R + r0 + rl) * C + c0 + lane));
    }
    __syncthreads();
#pragma unroll
    for (int j = 0; j < 16; ++j) {
        int cl = j * 4 + grp;
        dst[((size_t)b * C + c0 + cl) * R + r0 + lane] = t[lane][cl];
    }
}

__global__ __launch_bounds__(256) void k_prep(
    const void* inw, const void* xpw, const void* opw, const void* spw,
    const void* cw, const void* cb, const void* dtw, const void* alog,
    const void* dtb, const void* Dw,
    const void* sg, const void* sb, const void* sm, const void* sv,
    const void* rg, const void* rb, const void* rm, const void* rv,
    const void* lg, const void* lb,
    const void* scp, const void* resnet,
    u16* __restrict__ w16, u16* __restrict__ scpT, u16* __restrict__ resnetT)
{
    bool f32 = detect_f32((const u16*)resnet);
    int bid = blockIdx.x, tid = threadIdx.x;
    if (bid < 2230) {
        int i = bid * 256 + tid;             // i < 570880 = N_CVT exactly
        const void* src; int off = i;
        if      (i < O_XPW)  { src = inw; }
        else if (i < O_OPW)  { src = xpw;  off = i - O_XPW; }
        else if (i < O_SPW)  { src = opw;  off = i - O_OPW; }
        else if (i < O_CW)   { src = spw;  off = i - O_SPW; }
        else if (i < O_CB)   { src = cw;   off = i - O_CW; }
        else if (i < O_DTW)  { src = cb;   off = i - O_CB; }
        else if (i < O_ALOG) { src = dtw;  off = i - O_DTW; }
        else if (i < O_DTB)  { src = alog; off = i - O_ALOG; }
        else if (i < O_DW)   { src = dtb;  off = i - O_DTB; }
        else if (i < O_SG)   { src = Dw;   off = i - O_DW; }
        else if (i < O_SB)   { src = sg;   off = i - O_SG; }
        else if (i < O_SM)   { src = sb;   off = i - O_SB; }
        else if (i < O_SV)   { src = sm;   off = i - O_SM; }
        else if (i < O_RG)   { src = sv;   off = i - O_SV; }
        else if (i < O_RB)   { src = rg;   off = i - O_RG; }
        else if (i < O_RM)   { src = rb;   off = i - O_RB; }
        else if (i < O_RV)   { src = rm;   off = i - O_RM; }
        else if (i < O_LG)   { src = rv;   off = i - O_RV; }
        else if (i < O_LB)   { src = lg;   off = i - O_LG; }
        else                 { src = lb;   off = i - O_LB; }
        w16[i] = f2b(ld_any(f32, src, off));
    } else if (bid < 2230 + 256) {
        int t = bid - 2230;                  // scp: R=512, C=1024
        tr_tile(f32, scp, scpT, 512, 1024, (t & 15) * 64, ((t >> 4) & 7) * 64, t >> 7, tid);
    } else {
        int t = bid - 2486;                  // resnet: R=256, C=4096
        tr_tile(f32, resnet, resnetT, 256, 4096, (t & 63) * 64, ((t >> 6) & 3) * 64, t >> 8, tid);
    }
}

// ---------------------------------------------------------------------------
// k_scpmm: sp16[p][o] = BN(sum_c scpT[p][c] * spw[o][c]). MFMA, all bf16.
// M=2048, N=256, K=512. grid (32, 4), block 256 (4 waves 2x2).
// ---------------------------------------------------------------------------
__global__ __launch_bounds__(256) void k_scpmm(
    const u16* __restrict__ scpT, const u16* __restrict__ w16,
    u16* __restrict__ sp16)
{
    const int N = 256, K = 512;
    int tid = threadIdx.x, lane = tid & 63, wid = tid >> 6;
    int ln = lane & 15, q = lane >> 4;
    int m0 = blockIdx.x * 64 + (wid & 1) * 32;
    int n0 = blockIdx.y * 64 + (wid >> 1) * 32;
    f32x4 acc00 = {0.f,0.f,0.f,0.f}, acc01 = acc00, acc10 = acc00, acc11 = acc00;
    const u16* Ap0 = scpT + (size_t)(m0 + ln) * K + q * 8;
    const u16* Ap1 = Ap0 + (size_t)16 * K;
    const u16* Wp = w16 + O_SPW;
#pragma unroll 4
    for (int k0 = 0; k0 < K; k0 += 32) {
        int kk = k0 + q * 8;
        short8 a0 = *reinterpret_cast<const short8*>(Ap0 + k0);
        short8 a1 = *reinterpret_cast<const short8*>(Ap1 + k0);
        short8 b0 = *reinterpret_cast<const short8*>(Wp + (size_t)(n0 + ln) * K + kk);
        short8 b1 = *reinterpret_cast<const short8*>(Wp + (size_t)(n0 + ln + 16) * K + kk);
        acc00 = __builtin_amdgcn_mfma_f32_16x16x32_bf16(a0, b0, acc00, 0, 0, 0);
        acc01 = __builtin_amdgcn_mfma_f32_16x16x32_bf16(a0, b1, acc01, 0, 0, 0);
        acc10 = __builtin_amdgcn_mfma_f32_16x16x32_bf16(a1, b0, acc10, 0, 0, 0);
        acc11 = __builtin_amdgcn_mfma_f32_16x16x32_bf16(a1, b1, acc11, 0, 0, 0);
    }
    int r0 = m0 + q * 4, c0 = n0 + ln;
    float inv0 = b2f(w16[O_SG + c0]) * rsqrtf(b2f(w16[O_SV + c0]) + 1e-5f);
    float sh0  = b2f(w16[O_SB + c0]) - b2f(w16[O_SM + c0]) * inv0;
    float inv1 = b2f(w16[O_SG + c0 + 16]) * rsqrtf(b2f(w16[O_SV + c0 + 16]) + 1e-5f);
    float sh1  = b2f(w16[O_SB + c0 + 16]) - b2f(w16[O_SM + c0 + 16]) * inv1;
#pragma unroll
    for (int r = 0; r < 4; ++r) {
        sp16[(size_t)(r0 + r) * N + c0]           = f2b(acc00[r] * inv0 + sh0);
        sp16[(size_t)(r0 + r) * N + c0 + 16]      = f2b(acc01[r] * inv1 + sh1);
        sp16[(size_t)(r0 + 16 + r) * N + c0]      = f2b(acc10[r] * inv0 + sh0);
        sp16[(size_t)(r0 + 16 + r) * N + c0 + 16] = f2b(acc11[r] * inv1 + sh1);
    }
}

// ---------------------------------------------------------------------------
// k_ln: res-BN + bilinear + add -> LayerNorm -> xn. 8 rows per block.
// grid (512, B), block 256 (thread = channel).
// ---------------------------------------------------------------------------
__global__ __launch_bounds__(256) void k_ln(
    const u16* __restrict__ resnetT, const u16* __restrict__ w16,
    const u16* __restrict__ sp16, u16* __restrict__ xn)
{
    __shared__ float red[8];
    int c = threadIdx.x, b = blockIdx.y;
    float inv = b2f(w16[O_RG + c]) * rsqrtf(b2f(w16[O_RV + c]) + 1e-5f);
    float sh  = b2f(w16[O_RB + c]) - b2f(w16[O_RM + c]) * inv;
    float lgv = b2f(w16[O_LG + c]), lbv = b2f(w16[O_LB + c]);
    const u16* spc = sp16 + (size_t)b * 1024 * 256 + c;
    for (int j = 0; j < 8; ++j) {
        int l = blockIdx.x * 8 + j;
        int h = l >> 6, w = l & 63;
        float rr = b2f(resnetT[((size_t)b * 4096 + l) * 256 + c]);
        float rn = rr * inv + sh;
        float xh = 0.5f * h - 0.25f; int jh = (int)floorf(xh); float fh = xh - jh;
        float xw = 0.5f * w - 0.25f; int jw = (int)floorf(xw); float fw = xw - jw;
        int h0 = jh < 0 ? 0 : jh, h1 = jh + 1 > 31 ? 31 : jh + 1;
        int w0 = jw < 0 ? 0 : jw, w1 = jw + 1 > 31 ? 31 : jw + 1;
        float v00 = b2f(spc[(size_t)(h0 * 32 + w0) * 256]), v01 = b2f(spc[(size_t)(h0 * 32 + w1) * 256]);
        float v10 = b2f(spc[(size_t)(h1 * 32 + w0) * 256]), v11 = b2f(spc[(size_t)(h1 * 32 + w1) * 256]);
        float sp = (1.f - fh) * ((1.f - fw) * v00 + fw * v01)
                 + fh * ((1.f - fw) * v10 + fw * v11);
        float fv = rn + sp;

        float s = fv, s2 = fv * fv;
#pragma unroll
        for (int off = 1; off < 64; off <<= 1) {
            s  += __shfl_xor(s, off);
            s2 += __shfl_xor(s2, off);
        }
        int wv = c >> 6;
        if ((c & 63) == 0) { red[wv] = s; red[4 + wv] = s2; }
        __syncthreads();
        float S  = red[0] + red[1] + red[2] + red[3];
        float S2 = red[4] + red[5] + red[6] + red[7];
        __syncthreads();
        float mu   = S * (1.f / 256.f);
        float var  = S2 * (1.f / 256.f) - mu * mu;
        float rstd = rsqrtf(var + 1e-5f);
        xn[((size_t)b * 4096 + l) * 256 + c] = f2b((fv - mu) * rstd * lgv + lbv);
    }
}

// ---------------------------------------------------------------------------
// in_proj GEMM, both halves: xz[row][n], n in [0,1024). M=8192, K=256.
// Block tile 128m x 128n (4 waves 2x2), wave tile 64x64 (16 MFMA/k-iter).
// grid (64, 8), block 256.
// ---------------------------------------------------------------------------
__global__ __launch_bounds__(256) void k_gemm_in(
    const u16* __restrict__ A, const u16* __restrict__ w16, u16* __restrict__ Out)
{
    const int N = 1024, K = 256;
    int tid = threadIdx.x, lane = tid & 63, wid = tid >> 6;
    int ln = lane & 15, q = lane >> 4;
    int m0 = blockIdx.x * 128 + (wid & 1) * 64;
    int n0 = blockIdx.y * 128 + (wid >> 1) * 64;
    f32x4 acc[4][4];
#pragma unroll
    for (int i = 0; i < 4; ++i)
#pragma unroll
        for (int j = 0; j < 4; ++j) acc[i][j] = {0.f,0.f,0.f,0.f};
    const u16* Ap = A + (size_t)(m0 + ln) * K + q * 8;
    const u16* Bp = w16 + O_INW + (size_t)(n0 + ln) * K + q * 8;
#pragma unroll
    for (int k0 = 0; k0 < K; k0 += 32) {
        short8 a[4], bb[4];
#pragma unroll
        for (int i = 0; i < 4; ++i)
            a[i] = *reinterpret_cast<const short8*>(Ap + (size_t)(16 * i) * K + k0);
#pragma unroll
        for (int j = 0; j < 4; ++j)
            bb[j] = *reinterpret_cast<const short8*>(Bp + (size_t)(16 * j) * K + k0);
#pragma unroll
        for (int i = 0; i < 4; ++i)
#pragma unroll
            for (int j = 0; j < 4; ++j)
                acc[i][j] = __builtin_amdgcn_mfma_f32_16x16x32_bf16(a[i], bb[j], acc[i][j], 0, 0, 0);
    }
    int r0 = m0 + q * 4, c0 = n0 + ln;
#pragma unroll
    for (int i = 0; i < 4; ++i)
#pragma unroll
        for (int j = 0; j < 4; ++j)
#pragma unroll
            for (int r = 0; r < 4; ++r)
                Out[(size_t)(r0 + 16 * i + r) * N + c0 + 16 * j] = f2b(acc[i][j][r]);
}

// ---------------------------------------------------------------------------
// on-the-fly u fragment: u[row][kk0..kk0+8) = silu(causal conv3 of xm half of xz)
// ---------------------------------------------------------------------------
DEVINL short8 u_frag(const u16* __restrict__ xz, const u16* __restrict__ w16,
                     int row, int kk0)
{
    int l = row & 4095;
    const u16* p = xz + (size_t)row * 1024 + kk0;
    short8 zz = {0,0,0,0,0,0,0,0};
    short8 x0 = *reinterpret_cast<const short8*>(p);
    short8 x1 = (l >= 1) ? *reinterpret_cast<const short8*>(p - 1024) : zz;
    short8 x2 = (l >= 2) ? *reinterpret_cast<const short8*>(p - 2048) : zz;
    short8 r;
#pragma unroll
    for (int j = 0; j < 8; ++j) {
        int d = kk0 + j;
        float acc = b2f(w16[O_CB + d])
                  + b2f((u16)x2[j]) * b2f(w16[O_CW + d * 3])
                  + b2f((u16)x1[j]) * b2f(w16[O_CW + d * 3 + 1])
                  + b2f((u16)x0[j]) * b2f(w16[O_CW + d * 3 + 2]);
        r[j] = (short)f2b(silu(acc));
    }
    return r;
}

// ---------------------------------------------------------------------------
// x_proj GEMM, conv-on-the-fly A: xdf[row][n] f32, N=48, K=512.
// grid (256), block 128: 2 waves x 16-row tiles.
// ---------------------------------------------------------------------------
__global__ __launch_bounds__(128) void k_xproj(
    const u16* __restrict__ xz, const u16* __restrict__ w16, float* __restrict__ xdf)
{
    int tid = threadIdx.x, lane = tid & 63, wid = tid >> 6;
    int ln = lane & 15, q = lane >> 4;
    int m0 = blockIdx.x * 32 + wid * 16;
    const u16* Wp = w16 + O_XPW;
    f32x4 acc[3];
#pragma unroll
    for (int j = 0; j < 3; ++j) acc[j] = {0.f,0.f,0.f,0.f};
    for (int k0 = 0; k0 < 512; k0 += 32) {
        int kk0 = k0 + q * 8;
        short8 a0 = u_frag(xz, w16, m0 + ln, kk0);
#pragma unroll
        for (int j = 0; j < 3; ++j) {
            short8 bj = *reinterpret_cast<const short8*>(Wp + (size_t)(16 * j + ln) * 512 + kk0);
            acc[j] = __builtin_amdgcn_mfma_f32_16x16x32_bf16(a0, bj, acc[j], 0, 0, 0);
        }
    }
#pragma unroll
    for (int j = 0; j < 3; ++j)
#pragma unroll
        for (int r = 0; r < 4; ++r)
            xdf[(size_t)(m0 + q * 4 + r) * 48 + 16 * j + ln] = acc[j][r];
}

// dt = softplus(dot(xd[0:16], wdt) + bias), vector LDS reads
DEVINL float dt_of4(const f32x4* xd4, const f32x4* wdt4, float bias) {
    float acc = bias;
#pragma unroll
    for (int j = 0; j < 4; ++j) {
        f32x4 v = xd4[j], w = wdt4[j];
        acc += v[0]*w[0] + v[1]*w[1] + v[2]*w[2] + v[3]*w[3];
    }
    return acc > 15.f ? acc : __logf(1.f + __expf(acc));
}

// ---------------------------------------------------------------------------
// scan1: per-chunk local scan, conv-on-the-fly. grid (NC, B), block 512.
// xd accessed via f32x4 (ds_read_b128).
// ---------------------------------------------------------------------------
__global__ __launch_bounds__(512) void k_scan1(
    const u16* __restrict__ xz, const float* __restrict__ xdf,
    const u16* __restrict__ w16, u16* __restrict__ cA, u16* __restrict__ cH,
    int NC, int CL)
{
    __shared__ float xds[32][48];
    int d = threadIdx.x, ck = blockIdx.x, b = blockIdx.y;
    float a[16], h[16], ap[16];
    f32x4 wdt4[4];
#pragma unroll
    for (int j = 0; j < 4; ++j) {
#pragma unroll
        for (int r = 0; r < 4; ++r) wdt4[j][r] = b2f(w16[O_DTW + d * 16 + 4 * j + r]);
    }
#pragma unroll
    for (int s = 0; s < 16; ++s) {
        a[s] = -__expf(b2f(w16[O_ALOG + d * 16 + s]));
        h[s] = 0.f; ap[s] = 1.f;
    }
    float bias = b2f(w16[O_DTB + d]);
    float cw0 = b2f(w16[O_CW + d * 3]), cw1 = b2f(w16[O_CW + d * 3 + 1]),
          cw2 = b2f(w16[O_CW + d * 3 + 2]), cbv = b2f(w16[O_CB + d]);
    int l0 = ck * CL;
    size_t xbase = ((size_t)b * 4096 + l0) * 1024 + d;
    float x2 = (l0 >= 2) ? b2f(xz[xbase - 2048]) : 0.f;
    float x1 = (l0 >= 1) ? b2f(xz[xbase - 1024]) : 0.f;
    for (int t0 = 0; t0 < CL; t0 += 32) {
        __syncthreads();
#pragma unroll
        for (int k = 0; k < 3; ++k) {
            int idx = k * 512 + d;
            int r = idx / 48, c = idx - r * 48;
            xds[r][c] = xdf[((size_t)b * 4096 + l0 + t0 + r) * 48 + c];
        }
        __syncthreads();
        for (int il = 0; il < 32; ++il) {
            float x0 = b2f(xz[xbase + (size_t)(t0 + il) * 1024]);
            float uv = silu(cbv + cw0 * x2 + cw1 * x1 + cw2 * x0);
            const f32x4* xd4 = reinterpret_cast<const f32x4*>(xds[il]);
            float dtv = dt_of4(xd4, wdt4, bias);
            float du = dtv * uv;
            f32x4 Bv[4];
#pragma unroll
            for (int j = 0; j < 4; ++j) Bv[j] = xd4[4 + j];
#pragma unroll
            for (int s = 0; s < 16; ++s) {
                float dA = __expf(dtv * a[s]);
                h[s]  = dA * h[s] + du * Bv[s >> 2][s & 3];
                ap[s] *= dA;
            }
            x2 = x1; x1 = x0;
        }
    }
    size_t base = (((size_t)b * NC + ck) * 16) * 512 + d;
#pragma unroll
    for (int s = 0; s < 16; ++s) {
        cA[base + (size_t)s * 512] = f2b(ap[s]);
        cH[base + (size_t)s * 512] = f2b(h[s]);
    }
}

// ---------------------------------------------------------------------------
// scan2: cross-chunk recurrence; cH[ck] := h_in(ck). grid (16, 4, B), block 128.
// ---------------------------------------------------------------------------
__global__ __launch_bounds__(128) void k_scan2(const u16* __restrict__ cA,
                                               u16* __restrict__ cH, int NC)
{
    int d = blockIdx.y * 128 + threadIdx.x, s = blockIdx.x, b = blockIdx.z;
    float h = 0.f;
#pragma unroll 4
    for (int ck = 0; ck < NC; ++ck) {
        size_t idx = (((size_t)b * NC + ck) * 16 + s) * 512 + d;
        float aP = b2f(cA[idx]), hE = b2f(cH[idx]);
        cH[idx] = f2b(h);
        h = aP * h + hE;
    }
}

// ---------------------------------------------------------------------------
// scan3: replay from h_in, conv-on-the-fly; y = (h.C + u*D) * silu(z).
// grid (NC, B), block 512. f32x4 LDS reads.
// ---------------------------------------------------------------------------
__global__ __launch_bounds__(512) void k_scan3(
    const u16* __restrict__ xz, const float* __restrict__ xdf,
    const u16* __restrict__ w16, const u16* __restrict__ cH,
    u16* __restrict__ y, int NC, int CL)
{
    __shared__ float xds[32][48];
    int d = threadIdx.x, ck = blockIdx.x, b = blockIdx.y;
    float a[16], h[16];
    f32x4 wdt4[4];
#pragma unroll
    for (int j = 0; j < 4; ++j) {
#pragma unroll
        for (int r = 0; r < 4; ++r) wdt4[j][r] = b2f(w16[O_DTW + d * 16 + 4 * j + r]);
    }
    size_t base = (((size_t)b * NC + ck) * 16) * 512 + d;
#pragma unroll
    for (int s = 0; s < 16; ++s) {
        a[s] = -__expf(b2f(w16[O_ALOG + d * 16 + s]));
        h[s] = b2f(cH[base + (size_t)s * 512]);
    }
    float bias = b2f(w16[O_DTB + d]);
    float Dv = b2f(w16[O_DW + d]);
    float cw0 = b2f(w16[O_CW + d * 3]), cw1 = b2f(w16[O_CW + d * 3 + 1]),
          cw2 = b2f(w16[O_CW + d * 3 + 2]), cbv = b2f(w16[O_CB + d]);
    int l0 = ck * CL;
    size_t xbase = ((size_t)b * 4096 + l0) * 1024 + d;
    float x2 = (l0 >= 2) ? b2f(xz[xbase - 2048]) : 0.f;
    float x1 = (l0 >= 1) ? b2f(xz[xbase - 1024]) : 0.f;
    for (int t0 = 0; t0 < CL; t0 += 32) {
        __syncthreads();
#pragma unroll
        for (int k = 0; k < 3; ++k) {
            int idx = k * 512 + d;
            int r = idx / 48, c = idx - r * 48;
            xds[r][c] = xdf[((size_t)b * 4096 + l0 + t0 + r) * 48 + c];
        }
        __syncthreads();
        for (int il = 0; il < 32; ++il) {
            size_t row = (size_t)b * 4096 + l0 + t0 + il;
            float x0 = b2f(xz[xbase + (size_t)(t0 + il) * 1024]);
            float uv = silu(cbv + cw0 * x2 + cw1 * x1 + cw2 * x0);
            const f32x4* xd4 = reinterpret_cast<const f32x4*>(xds[il]);
            float dtv = dt_of4(xd4, wdt4, bias);
            float du = dtv * uv;
            f32x4 Bv[4], Cv[4];
#pragma unroll
            for (int j = 0; j < 4; ++j) { Bv[j] = xd4[4 + j]; Cv[j] = xd4[8 + j]; }
            float yv = 0.f;
#pragma unroll
            for (int s = 0; s < 16; ++s) {
                float dA = __expf(dtv * a[s]);
                h[s] = dA * h[s] + du * Bv[s >> 2][s & 3];
                yv += h[s] * Cv[s >> 2][s & 3];
            }
            yv += uv * Dv;
            float zv = b2f(xz[row * 1024 + 512 + d]);
            yv *= silu(zv);
            y[row * 512 + d] = f2b(yv);
            x2 = x1; x1 = x0;
        }
    }
}

// ---------------------------------------------------------------------------
// out_proj GEMM (m = channel, n = sequence) + fused-recompute epilogue.
// Block tile 128chan x 128seq (4 waves 2x2), wave 64x64. grid (2, 64), block 256.
// ---------------------------------------------------------------------------
template<bool F32> DEVINL void out_body(
    const u16* Y, const u16* w16, const void* resnet,
    const u16* sp16, void* outp)
{
    const int K = 512;
    int tid = threadIdx.x, lane = tid & 63, wid = tid >> 6;
    int ln = lane & 15, q = lane >> 4;
    int m0 = blockIdx.x * 128 + (wid & 1) * 64;   // channel dim (256)
    int n0 = blockIdx.y * 128 + (wid >> 1) * 64;  // sequence dim (8192)
    f32x4 acc[4][4];
#pragma unroll
    for (int i = 0; i < 4; ++i)
#pragma unroll
        for (int j = 0; j < 4; ++j) acc[i][j] = {0.f,0.f,0.f,0.f};
    const u16* Ap = w16 + O_OPW + (size_t)(m0 + ln) * K + q * 8;
    const u16* Bp = Y + (size_t)(n0 + ln) * K + q * 8;
#pragma unroll 4
    for (int k0 = 0; k0 < K; k0 += 32) {
        short8 a[4], bb[4];
#pragma unroll
        for (int i = 0; i < 4; ++i)
            a[i] = *reinterpret_cast<const short8*>(Ap + (size_t)(16 * i) * K + k0);
#pragma unroll
        for (int j = 0; j < 4; ++j)
            bb[j] = *reinterpret_cast<const short8*>(Bp + (size_t)(16 * j) * K + k0);
#pragma unroll
        for (int i = 0; i < 4; ++i)
#pragma unroll
            for (int j = 0; j < 4; ++j)
                acc[i][j] = __builtin_amdgcn_mfma_f32_16x16x32_bf16(a[i], bb[j], acc[i][j], 0, 0, 0);
    }
    int r0 = m0 + q * 4;
    int nb = n0 + ln;
    float inv16[4][4], sh16[4][4];
#pragma unroll
    for (int im = 0; im < 4; ++im)
#pragma unroll
        for (int r = 0; r < 4; ++r) {
            int c = r0 + 16 * im + r;
            float inv = b2f(w16[O_RG + c]) * rsqrtf(b2f(w16[O_RV + c]) + 1e-5f);
            inv16[im][r] = inv;
            sh16[im][r]  = b2f(w16[O_RB + c]) - b2f(w16[O_RM + c]) * inv;
        }
#pragma unroll
    for (int jn = 0; jn < 4; ++jn) {
        int n = nb + 16 * jn;
        int b = n >> 12, l = n & 4095;
        int hh = l >> 6, w = l & 63;
        float xh = 0.5f * hh - 0.25f; int jh = (int)floorf(xh); float fh = xh - jh;
        float xw = 0.5f * w - 0.25f;  int jw = (int)floorf(xw); float fw = xw - jw;
        int h0 = jh < 0 ? 0 : jh, h1 = jh + 1 > 31 ? 31 : jh + 1;
        int w0 = jw < 0 ? 0 : jw, w1 = jw + 1 > 31 ? 31 : jw + 1;
        float w00 = (1.f - fh) * (1.f - fw), w01 = (1.f - fh) * fw;
        float w10 = fh * (1.f - fw),         w11 = fh * fw;
        const u16* spb = sp16 + (size_t)b * 1024 * 256;
#pragma unroll
        for (int im = 0; im < 4; ++im) {
            int cb = r0 + 16 * im;
            u16x4 s00 = *reinterpret_cast<const u16x4*>(spb + (size_t)(h0 * 32 + w0) * 256 + cb);
            u16x4 s01 = *reinterpret_cast<const u16x4*>(spb + (size_t)(h0 * 32 + w1) * 256 + cb);
            u16x4 s10 = *reinterpret_cast<const u16x4*>(spb + (size_t)(h1 * 32 + w0) * 256 + cb);
            u16x4 s11 = *reinterpret_cast<const u16x4*>(spb + (size_t)(h1 * 32 + w1) * 256 + cb);
#pragma unroll
            for (int r = 0; r < 4; ++r) {
                int c = cb + r;
                float rr = LDs<F32>(resnet, ((size_t)b * 256 + c) * 4096 + l);
                float sp = w00 * b2f(s00[r]) + w01 * b2f(s01[r])
                         + w10 * b2f(s10[r]) + w11 * b2f(s11[r]);
                float val = acc[im][jn][r] + rr * inv16[im][r] + sh16[im][r] + sp;
                size_t oi = ((size_t)b * 256 + c) * 4096 + l;
                if constexpr (F32) ((float*)outp)[oi] = val;
                else               ((u16*)outp)[oi]  = f2b(val);
            }
        }
    }
}
__global__ __launch_bounds__(256) void k_out(
    const u16* Y, const u16* w16, const void* resnet,
    const u16* sp16, void* outp)
{
    if (detect_f32((const u16*)resnet)) out_body<true>(Y, w16, resnet, sp16, outp);
    else                                out_body<false>(Y, w16, resnet, sp16, outp);
}

// ---------------------------------------------------------------------------
extern "C" void kernel_launch(void* const* d_in, const int* in_sizes, int n_in,
                              void* d_out, int out_size, void* d_ws, size_t ws_size,
                              hipStream_t stream)
{
    const void* resnet = d_in[0];
    const void* scp    = d_in[1];
    const void* spw    = d_in[2];
    const void* sg     = d_in[3];
    const void* sb     = d_in[4];
    const void* sm     = d_in[5];
    const void* sv     = d_in[6];
    const void* rg     = d_in[7];
    const void* rb     = d_in[8];
    const void* rm     = d_in[9];
    const void* rv     = d_in[10];
    const void* lg     = d_in[11];
    const void* lb     = d_in[12];
    const void* inw    = d_in[13];
    const void* cw     = d_in[14];
    const void* cb     = d_in[15];
    const void* xpw    = d_in[16];
    const void* dtw    = d_in[17];
    const void* dtb    = d_in[18];
    const void* alog   = d_in[19];
    const void* Dw     = d_in[20];
    const void* opw    = d_in[21];

    // Workspace layout (~52 MB of the 256 MiB ws)
    char*  ws      = (char*)d_ws;
    u16*   w16     = (u16*)(ws + 4096);         // 1.09 MB arena
    u16*   sp16    = (u16*)(ws + 2097152);      // 1 MB
    u16*   scpT    = (u16*)(ws + 4194304);      // 2 MB
    u16*   resnetT = (u16*)(ws + 8388608);      // 4 MB
    u16*   xn      = (u16*)(ws + 12582912);     // 4 MB
    u16*   xz      = (u16*)(ws + 16777216);     // 16 MB [b][l][1024] (xm | z)
    float* xdf     = (float*)(ws + 33554432);   // 1.5 MB f32 [b][l][48]
    u16*   y       = (u16*)(ws + 35651584);     // 8 MB
    const size_t tail0 = 44040192;

    int NC = 16;
    for (int cand = 128; cand >= 16; cand >>= 1) {
        if (tail0 + (size_t)cand * 65536 <= ws_size) { NC = cand; break; }
    }
    int CL = 4096 / NC;
    u16* cA = (u16*)(ws + tail0);
    u16* cH = (u16*)(ws + tail0 + (size_t)NC * 32768);

    k_prep<<<dim3(2998), 256, 0, stream>>>(
        inw, xpw, opw, spw, cw, cb, dtw, alog, dtb, Dw,
        sg, sb, sm, sv, rg, rb, rm, rv, lg, lb,
        scp, resnet, w16, scpT, resnetT);
    k_scpmm<<<dim3(32, 4), 256, 0, stream>>>(scpT, w16, sp16);
    k_ln<<<dim3(512, 2), 256, 0, stream>>>(resnetT, w16, sp16, xn);
    k_gemm_in<<<dim3(64, 8), 256, 0, stream>>>(xn, w16, xz);
    k_xproj<<<dim3(256), 128, 0, stream>>>(xz, w16, xdf);
    k_scan1<<<dim3(NC, 2), 512, 0, stream>>>(xz, xdf, w16, cA, cH, NC, CL);
    k_scan2<<<dim3(16, 4, 2), 128, 0, stream>>>(cA, cH, NC);
    k_scan3<<<dim3(NC, 2), 512, 0, stream>>>(xz, xdf, w16, cH, y, NC, CL);
    k_out<<<dim3(2, 64), 256, 0, stream>>>(y, w16, resnet, sp16, d_out);
}

// Round 11
// 262.399 us; speedup vs baseline: 1.0538x; 1.0538x over previous
//
#include <hip/hip_runtime.h>
#include <hip/hip_bf16.h>
#include <math.h>

typedef unsigned short u16;
typedef __attribute__((ext_vector_type(8))) short short8;
typedef __attribute__((ext_vector_type(4))) float f32x4;
typedef __attribute__((ext_vector_type(4))) unsigned short u16x4;

#define DEVINL static __device__ __forceinline__

DEVINL float b2f(u16 x) {
    union { unsigned u; float f; } v; v.u = ((unsigned)x) << 16; return v.f;
}
DEVINL u16 f2b(float f) {
    union { unsigned u; float f; } v; v.f = f;
    unsigned u = v.u;
    return (u16)((u + 0x7fffu + ((u >> 16) & 1u)) >> 16);
}
DEVINL float silu(float x) { return x / (1.f + __expf(-x)); }
DEVINL float ld_any(bool f32, const void* p, size_t i) {
    return f32 ? ((const float*)p)[i] : b2f(((const u16*)p)[i]);
}
template<bool F32> DEVINL float LDs(const void* p, size_t i) {
    if constexpr (F32) return ((const float*)p)[i];
    else               return b2f(((const u16*)p)[i]);
}

// Inline dtype detect: sample the 64 EVEN u16s of resnet. f32 input -> even
// u16s are mantissa halves (~46% trigger each, P[none]~4e-18); bf16 -> 0.
DEVINL bool detect_f32(const u16* __restrict__ raw) {
    int cnt = 0;
#pragma unroll
    for (int i = 0; i < 64; ++i) {
        float v = b2f(raw[i * 2]);
        if (!(fabsf(v) <= 1e3f)) cnt++;
    }
    return cnt > 0;
}

// --- converted-weights arena: element offsets inside w16 (bf16) ---
#define O_INW  0        /* 1024*256 */
#define O_XPW  262144   /* 48*512 */
#define O_OPW  286720   /* 256*512 */
#define O_SPW  417792   /* 256*512 */
#define O_CW   548864   /* 512*3 */
#define O_CB   550400   /* 512 */
#define O_DTW  550912   /* 512*16 */
#define O_ALOG 559104   /* 512*16 */
#define O_DTB  567296   /* 512 */
#define O_DW   567808   /* 512 */
#define O_SG   568320
#define O_SB   568576
#define O_SM   568832
#define O_SV   569088
#define O_RG   569344
#define O_RB   569600
#define O_RM   569856
#define O_RV   570112
#define O_LG   570368
#define O_LB   570624
#define N_CVT  570880

// ---------------------------------------------------------------------------
// k_prep: weight/param cvt (blocks 0..2229) + scp transpose (2230..2485)
// + resnet transpose (2486..2997). Self-detects dtype.
// ---------------------------------------------------------------------------
DEVINL void tr_tile(bool f32, const void* src, u16* dst, int R, int C,
                    int c0, int r0, int b, int tid)
{
    __shared__ u16 t[64][66];
    int lane = tid & 63, grp = tid >> 6;
#pragma unroll
    for (int j = 0; j < 16; ++j) {
        int rl = j * 4 + grp;
        t[rl][lane] = f2b(ld_any(f32, src, ((size_t)b * R + r0 + rl) * C + c0 + lane));
    }
    __syncthreads();
#pragma unroll
    for (int j = 0; j < 16; ++j) {
        int cl = j * 4 + grp;
        dst[((size_t)b * C + c0 + cl) * R + r0 + lane] = t[lane][cl];
    }
}

__global__ __launch_bounds__(256) void k_prep(
    const void* inw, const void* xpw, const void* opw, const void* spw,
    const void* cw, const void* cb, const void* dtw, const void* alog,
    const void* dtb, const void* Dw,
    const void* sg, const void* sb, const void* sm, const void* sv,
    const void* rg, const void* rb, const void* rm, const void* rv,
    const void* lg, const void* lb,
    const void* scp, const void* resnet,
    u16* __restrict__ w16, u16* __restrict__ scpT, u16* __restrict__ resnetT)
{
    bool f32 = detect_f32((const u16*)resnet);
    int bid = blockIdx.x, tid = threadIdx.x;
    if (bid < 2230) {
        int i = bid * 256 + tid;             // i < 570880 = N_CVT exactly
        const void* src; int off = i;
        if      (i < O_XPW)  { src = inw; }
        else if (i < O_OPW)  { src = xpw;  off = i - O_XPW; }
        else if (i < O_SPW)  { src = opw;  off = i - O_OPW; }
        else if (i < O_CW)   { src = spw;  off = i - O_SPW; }
        else if (i < O_CB)   { src = cw;   off = i - O_CW; }
        else if (i < O_DTW)  { src = cb;   off = i - O_CB; }
        else if (i < O_ALOG) { src = dtw;  off = i - O_DTW; }
        else if (i < O_DTB)  { src = alog; off = i - O_ALOG; }
        else if (i < O_DW)   { src = dtb;  off = i - O_DTB; }
        else if (i < O_SG)   { src = Dw;   off = i - O_DW; }
        else if (i < O_SB)   { src = sg;   off = i - O_SG; }
        else if (i < O_SM)   { src = sb;   off = i - O_SB; }
        else if (i < O_SV)   { src = sm;   off = i - O_SM; }
        else if (i < O_RG)   { src = sv;   off = i - O_SV; }
        else if (i < O_RB)   { src = rg;   off = i - O_RG; }
        else if (i < O_RM)   { src = rb;   off = i - O_RB; }
        else if (i < O_RV)   { src = rm;   off = i - O_RM; }
        else if (i < O_LG)   { src = rv;   off = i - O_RV; }
        else if (i < O_LB)   { src = lg;   off = i - O_LG; }
        else                 { src = lb;   off = i - O_LB; }
        w16[i] = f2b(ld_any(f32, src, off));
    } else if (bid < 2230 + 256) {
        int t = bid - 2230;                  // scp: R=512, C=1024
        tr_tile(f32, scp, scpT, 512, 1024, (t & 15) * 64, ((t >> 4) & 7) * 64, t >> 7, tid);
    } else {
        int t = bid - 2486;                  // resnet: R=256, C=4096
        tr_tile(f32, resnet, resnetT, 256, 4096, (t & 63) * 64, ((t >> 6) & 3) * 64, t >> 8, tid);
    }
}

// ---------------------------------------------------------------------------
// k_scpmm: sp16[p][o] = BN(sum_c scpT[p][c] * spw[o][c]). MFMA, all bf16.
// M=2048, N=256, K=512. grid (32, 4), block 256 (4 waves 2x2).
// ---------------------------------------------------------------------------
__global__ __launch_bounds__(256) void k_scpmm(
    const u16* __restrict__ scpT, const u16* __restrict__ w16,
    u16* __restrict__ sp16)
{
    const int N = 256, K = 512;
    int tid = threadIdx.x, lane = tid & 63, wid = tid >> 6;
    int ln = lane & 15, q = lane >> 4;
    int m0 = blockIdx.x * 64 + (wid & 1) * 32;
    int n0 = blockIdx.y * 64 + (wid >> 1) * 32;
    f32x4 acc00 = {0.f,0.f,0.f,0.f}, acc01 = acc00, acc10 = acc00, acc11 = acc00;
    const u16* Ap0 = scpT + (size_t)(m0 + ln) * K + q * 8;
    const u16* Ap1 = Ap0 + (size_t)16 * K;
    const u16* Wp = w16 + O_SPW;
#pragma unroll 4
    for (int k0 = 0; k0 < K; k0 += 32) {
        int kk = k0 + q * 8;
        short8 a0 = *reinterpret_cast<const short8*>(Ap0 + k0);
        short8 a1 = *reinterpret_cast<const short8*>(Ap1 + k0);
        short8 b0 = *reinterpret_cast<const short8*>(Wp + (size_t)(n0 + ln) * K + kk);
        short8 b1 = *reinterpret_cast<const short8*>(Wp + (size_t)(n0 + ln + 16) * K + kk);
        acc00 = __builtin_amdgcn_mfma_f32_16x16x32_bf16(a0, b0, acc00, 0, 0, 0);
        acc01 = __builtin_amdgcn_mfma_f32_16x16x32_bf16(a0, b1, acc01, 0, 0, 0);
        acc10 = __builtin_amdgcn_mfma_f32_16x16x32_bf16(a1, b0, acc10, 0, 0, 0);
        acc11 = __builtin_amdgcn_mfma_f32_16x16x32_bf16(a1, b1, acc11, 0, 0, 0);
    }
    int r0 = m0 + q * 4, c0 = n0 + ln;
    float inv0 = b2f(w16[O_SG + c0]) * rsqrtf(b2f(w16[O_SV + c0]) + 1e-5f);
    float sh0  = b2f(w16[O_SB + c0]) - b2f(w16[O_SM + c0]) * inv0;
    float inv1 = b2f(w16[O_SG + c0 + 16]) * rsqrtf(b2f(w16[O_SV + c0 + 16]) + 1e-5f);
    float sh1  = b2f(w16[O_SB + c0 + 16]) - b2f(w16[O_SM + c0 + 16]) * inv1;
#pragma unroll
    for (int r = 0; r < 4; ++r) {
        sp16[(size_t)(r0 + r) * N + c0]           = f2b(acc00[r] * inv0 + sh0);
        sp16[(size_t)(r0 + r) * N + c0 + 16]      = f2b(acc01[r] * inv1 + sh1);
        sp16[(size_t)(r0 + 16 + r) * N + c0]      = f2b(acc10[r] * inv0 + sh0);
        sp16[(size_t)(r0 + 16 + r) * N + c0 + 16] = f2b(acc11[r] * inv1 + sh1);
    }
}

// ---------------------------------------------------------------------------
// k_ln: res-BN + bilinear + add -> LayerNorm -> xn. 8 rows per block.
// grid (512, B), block 256 (thread = channel).
// ---------------------------------------------------------------------------
__global__ __launch_bounds__(256) void k_ln(
    const u16* __restrict__ resnetT, const u16* __restrict__ w16,
    const u16* __restrict__ sp16, u16* __restrict__ xn)
{
    __shared__ float red[8];
    int c = threadIdx.x, b = blockIdx.y;
    float inv = b2f(w16[O_RG + c]) * rsqrtf(b2f(w16[O_RV + c]) + 1e-5f);
    float sh  = b2f(w16[O_RB + c]) - b2f(w16[O_RM + c]) * inv;
    float lgv = b2f(w16[O_LG + c]), lbv = b2f(w16[O_LB + c]);
    const u16* spc = sp16 + (size_t)b * 1024 * 256 + c;
    for (int j = 0; j < 8; ++j) {
        int l = blockIdx.x * 8 + j;
        int h = l >> 6, w = l & 63;
        float rr = b2f(resnetT[((size_t)b * 4096 + l) * 256 + c]);
        float rn = rr * inv + sh;
        float xh = 0.5f * h - 0.25f; int jh = (int)floorf(xh); float fh = xh - jh;
        float xw = 0.5f * w - 0.25f; int jw = (int)floorf(xw); float fw = xw - jw;
        int h0 = jh < 0 ? 0 : jh, h1 = jh + 1 > 31 ? 31 : jh + 1;
        int w0 = jw < 0 ? 0 : jw, w1 = jw + 1 > 31 ? 31 : jw + 1;
        float v00 = b2f(spc[(size_t)(h0 * 32 + w0) * 256]), v01 = b2f(spc[(size_t)(h0 * 32 + w1) * 256]);
        float v10 = b2f(spc[(size_t)(h1 * 32 + w0) * 256]), v11 = b2f(spc[(size_t)(h1 * 32 + w1) * 256]);
        float sp = (1.f - fh) * ((1.f - fw) * v00 + fw * v01)
                 + fh * ((1.f - fw) * v10 + fw * v11);
        float fv = rn + sp;

        float s = fv, s2 = fv * fv;
#pragma unroll
        for (int off = 1; off < 64; off <<= 1) {
            s  += __shfl_xor(s, off);
            s2 += __shfl_xor(s2, off);
        }
        int wv = c >> 6;
        if ((c & 63) == 0) { red[wv] = s; red[4 + wv] = s2; }
        __syncthreads();
        float S  = red[0] + red[1] + red[2] + red[3];
        float S2 = red[4] + red[5] + red[6] + red[7];
        __syncthreads();
        float mu   = S * (1.f / 256.f);
        float var  = S2 * (1.f / 256.f) - mu * mu;
        float rstd = rsqrtf(var + 1e-5f);
        xn[((size_t)b * 4096 + l) * 256 + c] = f2b((fv - mu) * rstd * lgv + lbv);
    }
}

// ---------------------------------------------------------------------------
// in_proj GEMM, both halves: xz[row][n], n in [0,1024). M=8192, K=256.
// Block tile 128m x 128n (4 waves 2x2), wave tile 64x64 (16 MFMA/k-iter).
// grid (64, 8), block 256.
// ---------------------------------------------------------------------------
__global__ __launch_bounds__(256) void k_gemm_in(
    const u16* __restrict__ A, const u16* __restrict__ w16, u16* __restrict__ Out)
{
    const int N = 1024, K = 256;
    int tid = threadIdx.x, lane = tid & 63, wid = tid >> 6;
    int ln = lane & 15, q = lane >> 4;
    int m0 = blockIdx.x * 128 + (wid & 1) * 64;
    int n0 = blockIdx.y * 128 + (wid >> 1) * 64;
    f32x4 acc[4][4];
#pragma unroll
    for (int i = 0; i < 4; ++i)
#pragma unroll
        for (int j = 0; j < 4; ++j) acc[i][j] = {0.f,0.f,0.f,0.f};
    const u16* Ap = A + (size_t)(m0 + ln) * K + q * 8;
    const u16* Bp = w16 + O_INW + (size_t)(n0 + ln) * K + q * 8;
#pragma unroll
    for (int k0 = 0; k0 < K; k0 += 32) {
        short8 a[4], bb[4];
#pragma unroll
        for (int i = 0; i < 4; ++i)
            a[i] = *reinterpret_cast<const short8*>(Ap + (size_t)(16 * i) * K + k0);
#pragma unroll
        for (int j = 0; j < 4; ++j)
            bb[j] = *reinterpret_cast<const short8*>(Bp + (size_t)(16 * j) * K + k0);
#pragma unroll
        for (int i = 0; i < 4; ++i)
#pragma unroll
            for (int j = 0; j < 4; ++j)
                acc[i][j] = __builtin_amdgcn_mfma_f32_16x16x32_bf16(a[i], bb[j], acc[i][j], 0, 0, 0);
    }
    int r0 = m0 + q * 4, c0 = n0 + ln;
#pragma unroll
    for (int i = 0; i < 4; ++i)
#pragma unroll
        for (int j = 0; j < 4; ++j)
#pragma unroll
            for (int r = 0; r < 4; ++r)
                Out[(size_t)(r0 + 16 * i + r) * N + c0 + 16 * j] = f2b(acc[i][j][r]);
}

// ---------------------------------------------------------------------------
// on-the-fly u fragment: u[row][kk0..kk0+8) = silu(causal conv3 of xm half of xz)
// ---------------------------------------------------------------------------
DEVINL short8 u_frag(const u16* __restrict__ xz, const u16* __restrict__ w16,
                     int row, int kk0)
{
    int l = row & 4095;
    const u16* p = xz + (size_t)row * 1024 + kk0;
    short8 zz = {0,0,0,0,0,0,0,0};
    short8 x0 = *reinterpret_cast<const short8*>(p);
    short8 x1 = (l >= 1) ? *reinterpret_cast<const short8*>(p - 1024) : zz;
    short8 x2 = (l >= 2) ? *reinterpret_cast<const short8*>(p - 2048) : zz;
    short8 r;
#pragma unroll
    for (int j = 0; j < 8; ++j) {
        int d = kk0 + j;
        float acc = b2f(w16[O_CB + d])
                  + b2f((u16)x2[j]) * b2f(w16[O_CW + d * 3])
                  + b2f((u16)x1[j]) * b2f(w16[O_CW + d * 3 + 1])
                  + b2f((u16)x0[j]) * b2f(w16[O_CW + d * 3 + 2]);
        r[j] = (short)f2b(silu(acc));
    }
    return r;
}

// ---------------------------------------------------------------------------
// x_proj GEMM, conv-on-the-fly A: xdf[row][n] f32, N=48, K=512.
// grid (256), block 128: 2 waves x 16-row tiles.
// ---------------------------------------------------------------------------
__global__ __launch_bounds__(128) void k_xproj(
    const u16* __restrict__ xz, const u16* __restrict__ w16, float* __restrict__ xdf)
{
    int tid = threadIdx.x, lane = tid & 63, wid = tid >> 6;
    int ln = lane & 15, q = lane >> 4;
    int m0 = blockIdx.x * 32 + wid * 16;
    const u16* Wp = w16 + O_XPW;
    f32x4 acc[3];
#pragma unroll
    for (int j = 0; j < 3; ++j) acc[j] = {0.f,0.f,0.f,0.f};
    for (int k0 = 0; k0 < 512; k0 += 32) {
        int kk0 = k0 + q * 8;
        short8 a0 = u_frag(xz, w16, m0 + ln, kk0);
#pragma unroll
        for (int j = 0; j < 3; ++j) {
            short8 bj = *reinterpret_cast<const short8*>(Wp + (size_t)(16 * j + ln) * 512 + kk0);
            acc[j] = __builtin_amdgcn_mfma_f32_16x16x32_bf16(a0, bj, acc[j], 0, 0, 0);
        }
    }
#pragma unroll
    for (int j = 0; j < 3; ++j)
#pragma unroll
        for (int r = 0; r < 4; ++r)
            xdf[(size_t)(m0 + q * 4 + r) * 48 + 16 * j + ln] = acc[j][r];
}

// dt = softplus(dot(xd[0:16], wdt) + bias), vector LDS reads
DEVINL float dt_of4(const f32x4* xd4, const f32x4* wdt4, float bias) {
    float acc = bias;
#pragma unroll
    for (int j = 0; j < 4; ++j) {
        f32x4 v = xd4[j], w = wdt4[j];
        acc += v[0]*w[0] + v[1]*w[1] + v[2]*w[2] + v[3]*w[3];
    }
    return acc > 15.f ? acc : __logf(1.f + __expf(acc));
}

// ---------------------------------------------------------------------------
// scan1: per-chunk local scan, conv-on-the-fly. grid (NC, B), block 512.
// xd accessed via f32x4 (ds_read_b128).
// ---------------------------------------------------------------------------
__global__ __launch_bounds__(512) void k_scan1(
    const u16* __restrict__ xz, const float* __restrict__ xdf,
    const u16* __restrict__ w16, u16* __restrict__ cA, u16* __restrict__ cH,
    int NC, int CL)
{
    __shared__ float xds[32][48];
    int d = threadIdx.x, ck = blockIdx.x, b = blockIdx.y;
    float a[16], h[16], ap[16];
    f32x4 wdt4[4];
#pragma unroll
    for (int j = 0; j < 4; ++j) {
#pragma unroll
        for (int r = 0; r < 4; ++r) wdt4[j][r] = b2f(w16[O_DTW + d * 16 + 4 * j + r]);
    }
#pragma unroll
    for (int s = 0; s < 16; ++s) {
        a[s] = -__expf(b2f(w16[O_ALOG + d * 16 + s]));
        h[s] = 0.f; ap[s] = 1.f;
    }
    float bias = b2f(w16[O_DTB + d]);
    float cw0 = b2f(w16[O_CW + d * 3]), cw1 = b2f(w16[O_CW + d * 3 + 1]),
          cw2 = b2f(w16[O_CW + d * 3 + 2]), cbv = b2f(w16[O_CB + d]);
    int l0 = ck * CL;
    size_t xbase = ((size_t)b * 4096 + l0) * 1024 + d;
    float x2 = (l0 >= 2) ? b2f(xz[xbase - 2048]) : 0.f;
    float x1 = (l0 >= 1) ? b2f(xz[xbase - 1024]) : 0.f;
    for (int t0 = 0; t0 < CL; t0 += 32) {
        __syncthreads();
#pragma unroll
        for (int k = 0; k < 3; ++k) {
            int idx = k * 512 + d;
            int r = idx / 48, c = idx - r * 48;
            xds[r][c] = xdf[((size_t)b * 4096 + l0 + t0 + r) * 48 + c];
        }
        __syncthreads();
        for (int il = 0; il < 32; ++il) {
            float x0 = b2f(xz[xbase + (size_t)(t0 + il) * 1024]);
            float uv = silu(cbv + cw0 * x2 + cw1 * x1 + cw2 * x0);
            const f32x4* xd4 = reinterpret_cast<const f32x4*>(xds[il]);
            float dtv = dt_of4(xd4, wdt4, bias);
            float du = dtv * uv;
            f32x4 Bv[4];
#pragma unroll
            for (int j = 0; j < 4; ++j) Bv[j] = xd4[4 + j];
#pragma unroll
            for (int s = 0; s < 16; ++s) {
                float dA = __expf(dtv * a[s]);
                h[s]  = dA * h[s] + du * Bv[s >> 2][s & 3];
                ap[s] *= dA;
            }
            x2 = x1; x1 = x0;
        }
    }
    size_t base = (((size_t)b * NC + ck) * 16) * 512 + d;
#pragma unroll
    for (int s = 0; s < 16; ++s) {
        cA[base + (size_t)s * 512] = f2b(ap[s]);
        cH[base + (size_t)s * 512] = f2b(h[s]);
    }
}

// ---------------------------------------------------------------------------
// scan2: cross-chunk recurrence; cH[ck] := h_in(ck). grid (16, 4, B), block 128.
// ---------------------------------------------------------------------------
__global__ __launch_bounds__(128) void k_scan2(const u16* __restrict__ cA,
                                               u16* __restrict__ cH, int NC)
{
    int d = blockIdx.y * 128 + threadIdx.x, s = blockIdx.x, b = blockIdx.z;
    float h = 0.f;
#pragma unroll 4
    for (int ck = 0; ck < NC; ++ck) {
        size_t idx = (((size_t)b * NC + ck) * 16 + s) * 512 + d;
        float aP = b2f(cA[idx]), hE = b2f(cH[idx]);
        cH[idx] = f2b(h);
        h = aP * h + hE;
    }
}

// ---------------------------------------------------------------------------
// scan3: replay from h_in, conv-on-the-fly; y = (h.C + u*D) * silu(z).
// grid (NC, B), block 512. f32x4 LDS reads.
// ---------------------------------------------------------------------------
__global__ __launch_bounds__(512) void k_scan3(
    const u16* __restrict__ xz, const float* __restrict__ xdf,
    const u16* __restrict__ w16, const u16* __restrict__ cH,
    u16* __restrict__ y, int NC, int CL)
{
    __shared__ float xds[32][48];
    int d = threadIdx.x, ck = blockIdx.x, b = blockIdx.y;
    float a[16], h[16];
    f32x4 wdt4[4];
#pragma unroll
    for (int j = 0; j < 4; ++j) {
#pragma unroll
        for (int r = 0; r < 4; ++r) wdt4[j][r] = b2f(w16[O_DTW + d * 16 + 4 * j + r]);
    }
    size_t base = (((size_t)b * NC + ck) * 16) * 512 + d;
#pragma unroll
    for (int s = 0; s < 16; ++s) {
        a[s] = -__expf(b2f(w16[O_ALOG + d * 16 + s]));
        h[s] = b2f(cH[base + (size_t)s * 512]);
    }
    float bias = b2f(w16[O_DTB + d]);
    float Dv = b2f(w16[O_DW + d]);
    float cw0 = b2f(w16[O_CW + d * 3]), cw1 = b2f(w16[O_CW + d * 3 + 1]),
          cw2 = b2f(w16[O_CW + d * 3 + 2]), cbv = b2f(w16[O_CB + d]);
    int l0 = ck * CL;
    size_t xbase = ((size_t)b * 4096 + l0) * 1024 + d;
    float x2 = (l0 >= 2) ? b2f(xz[xbase - 2048]) : 0.f;
    float x1 = (l0 >= 1) ? b2f(xz[xbase - 1024]) : 0.f;
    for (int t0 = 0; t0 < CL; t0 += 32) {
        __syncthreads();
#pragma unroll
        for (int k = 0; k < 3; ++k) {
            int idx = k * 512 + d;
            int r = idx / 48, c = idx - r * 48;
            xds[r][c] = xdf[((size_t)b * 4096 + l0 + t0 + r) * 48 + c];
        }
        __syncthreads();
        for (int il = 0; il < 32; ++il) {
            size_t row = (size_t)b * 4096 + l0 + t0 + il;
            float x0 = b2f(xz[xbase + (size_t)(t0 + il) * 1024]);
            float uv = silu(cbv + cw0 * x2 + cw1 * x1 + cw2 * x0);
            const f32x4* xd4 = reinterpret_cast<const f32x4*>(xds[il]);
            float dtv = dt_of4(xd4, wdt4, bias);
            float du = dtv * uv;
            f32x4 Bv[4], Cv[4];
#pragma unroll
            for (int j = 0; j < 4; ++j) { Bv[j] = xd4[4 + j]; Cv[j] = xd4[8 + j]; }
            float yv = 0.f;
#pragma unroll
            for (int s = 0; s < 16; ++s) {
                float dA = __expf(dtv * a[s]);
                h[s] = dA * h[s] + du * Bv[s >> 2][s & 3];
                yv += h[s] * Cv[s >> 2][s & 3];
            }
            yv += uv * Dv;
            float zv = b2f(xz[row * 1024 + 512 + d]);
            yv *= silu(zv);
            y[row * 512 + d] = f2b(yv);
            x2 = x1; x1 = x0;
        }
    }
}

// ---------------------------------------------------------------------------
// out_proj GEMM (m = channel, n = sequence) + fused-recompute epilogue.
// Block tile 64chan x 128seq (4 waves 2x2), wave 32x64. grid (4, 64), block 256.
// (r9 shape: 256 blocks = 1/CU. r10's 128x128 tile halved the grid to 128
//  blocks -> half the CUs idle -> +9us. Reverted.)
// ---------------------------------------------------------------------------
template<bool F32> DEVINL void out_body(
    const u16* Y, const u16* w16, const void* resnet,
    const u16* sp16, void* outp)
{
    const int K = 512;
    int tid = threadIdx.x, lane = tid & 63, wid = tid >> 6;
    int ln = lane & 15, q = lane >> 4;
    int m0 = blockIdx.x * 64 + (wid & 1) * 32;    // channel dim (256)
    int n0 = blockIdx.y * 128 + (wid >> 1) * 64;  // sequence dim (8192)
    f32x4 acc[2][4];
#pragma unroll
    for (int i = 0; i < 2; ++i)
#pragma unroll
        for (int j = 0; j < 4; ++j) acc[i][j] = {0.f,0.f,0.f,0.f};
    const u16* Ap0 = w16 + O_OPW + (size_t)(m0 + ln) * K + q * 8;
    const u16* Ap1 = Ap0 + (size_t)16 * K;
    const u16* Bp  = Y + (size_t)(n0 + ln) * K + q * 8;
#pragma unroll 2
    for (int k0 = 0; k0 < K; k0 += 32) {
        short8 a0 = *reinterpret_cast<const short8*>(Ap0 + k0);
        short8 a1 = *reinterpret_cast<const short8*>(Ap1 + k0);
#pragma unroll
        for (int j = 0; j < 4; ++j) {
            short8 bj = *reinterpret_cast<const short8*>(Bp + (size_t)(16 * j) * K + k0);
            acc[0][j] = __builtin_amdgcn_mfma_f32_16x16x32_bf16(a0, bj, acc[0][j], 0, 0, 0);
            acc[1][j] = __builtin_amdgcn_mfma_f32_16x16x32_bf16(a1, bj, acc[1][j], 0, 0, 0);
        }
    }
    int r0 = m0 + q * 4;
    int nb = n0 + ln;
    float inv8[2][4], sh8[2][4];
#pragma unroll
    for (int im = 0; im < 2; ++im)
#pragma unroll
        for (int r = 0; r < 4; ++r) {
            int c = r0 + 16 * im + r;
            float inv = b2f(w16[O_RG + c]) * rsqrtf(b2f(w16[O_RV + c]) + 1e-5f);
            inv8[im][r] = inv;
            sh8[im][r]  = b2f(w16[O_RB + c]) - b2f(w16[O_RM + c]) * inv;
        }
#pragma unroll
    for (int jn = 0; jn < 4; ++jn) {
        int n = nb + 16 * jn;
        int b = n >> 12, l = n & 4095;
        int hh = l >> 6, w = l & 63;
        float xh = 0.5f * hh - 0.25f; int jh = (int)floorf(xh); float fh = xh - jh;
        float xw = 0.5f * w - 0.25f;  int jw = (int)floorf(xw); float fw = xw - jw;
        int h0 = jh < 0 ? 0 : jh, h1 = jh + 1 > 31 ? 31 : jh + 1;
        int w0 = jw < 0 ? 0 : jw, w1 = jw + 1 > 31 ? 31 : jw + 1;
        float w00 = (1.f - fh) * (1.f - fw), w01 = (1.f - fh) * fw;
        float w10 = fh * (1.f - fw),         w11 = fh * fw;
        const u16* spb = sp16 + (size_t)b * 1024 * 256;
#pragma unroll
        for (int im = 0; im < 2; ++im) {
            int cb = r0 + 16 * im;
            u16x4 s00 = *reinterpret_cast<const u16x4*>(spb + (size_t)(h0 * 32 + w0) * 256 + cb);
            u16x4 s01 = *reinterpret_cast<const u16x4*>(spb + (size_t)(h0 * 32 + w1) * 256 + cb);
            u16x4 s10 = *reinterpret_cast<const u16x4*>(spb + (size_t)(h1 * 32 + w0) * 256 + cb);
            u16x4 s11 = *reinterpret_cast<const u16x4*>(spb + (size_t)(h1 * 32 + w1) * 256 + cb);
#pragma unroll
            for (int r = 0; r < 4; ++r) {
                int c = cb + r;
                float rr = LDs<F32>(resnet, ((size_t)b * 256 + c) * 4096 + l);
                float sp = w00 * b2f(s00[r]) + w01 * b2f(s01[r])
                         + w10 * b2f(s10[r]) + w11 * b2f(s11[r]);
                float val = acc[im][jn][r] + rr * inv8[im][r] + sh8[im][r] + sp;
                size_t oi = ((size_t)b * 256 + c) * 4096 + l;
                if constexpr (F32) ((float*)outp)[oi] = val;
                else               ((u16*)outp)[oi]  = f2b(val);
            }
        }
    }
}
__global__ __launch_bounds__(256) void k_out(
    const u16* Y, const u16* w16, const void* resnet,
    const u16* sp16, void* outp)
{
    if (detect_f32((const u16*)resnet)) out_body<true>(Y, w16, resnet, sp16, outp);
    else                                out_body<false>(Y, w16, resnet, sp16, outp);
}

// ---------------------------------------------------------------------------
extern "C" void kernel_launch(void* const* d_in, const int* in_sizes, int n_in,
                              void* d_out, int out_size, void* d_ws, size_t ws_size,
                              hipStream_t stream)
{
    const void* resnet = d_in[0];
    const void* scp    = d_in[1];
    const void* spw    = d_in[2];
    const void* sg     = d_in[3];
    const void* sb     = d_in[4];
    const void* sm     = d_in[5];
    const void* sv     = d_in[6];
    const void* rg     = d_in[7];
    const void* rb     = d_in[8];
    const void* rm     = d_in[9];
    const void* rv     = d_in[10];
    const void* lg     = d_in[11];
    const void* lb     = d_in[12];
    const void* inw    = d_in[13];
    const void* cw     = d_in[14];
    const void* cb     = d_in[15];
    const void* xpw    = d_in[16];
    const void* dtw    = d_in[17];
    const void* dtb    = d_in[18];
    const void* alog   = d_in[19];
    const void* Dw     = d_in[20];
    const void* opw    = d_in[21];

    // Workspace layout (~52 MB of the 256 MiB ws)
    char*  ws      = (char*)d_ws;
    u16*   w16     = (u16*)(ws + 4096);         // 1.09 MB arena
    u16*   sp16    = (u16*)(ws + 2097152);      // 1 MB
    u16*   scpT    = (u16*)(ws + 4194304);      // 2 MB
    u16*   resnetT = (u16*)(ws + 8388608);      // 4 MB
    u16*   xn      = (u16*)(ws + 12582912);     // 4 MB
    u16*   xz      = (u16*)(ws + 16777216);     // 16 MB [b][l][1024] (xm | z)
    float* xdf     = (float*)(ws + 33554432);   // 1.5 MB f32 [b][l][48]
    u16*   y       = (u16*)(ws + 35651584);     // 8 MB
    const size_t tail0 = 44040192;

    int NC = 16;
    for (int cand = 128; cand >= 16; cand >>= 1) {
        if (tail0 + (size_t)cand * 65536 <= ws_size) { NC = cand; break; }
    }
    int CL = 4096 / NC;
    u16* cA = (u16*)(ws + tail0);
    u16* cH = (u16*)(ws + tail0 + (size_t)NC * 32768);

    k_prep<<<dim3(2998), 256, 0, stream>>>(
        inw, xpw, opw, spw, cw, cb, dtw, alog, dtb, Dw,
        sg, sb, sm, sv, rg, rb, rm, rv, lg, lb,
        scp, resnet, w16, scpT, resnetT);
    k_scpmm<<<dim3(32, 4), 256, 0, stream>>>(scpT, w16, sp16);
    k_ln<<<dim3(512, 2), 256, 0, stream>>>(resnetT, w16, sp16, xn);
    k_gemm_in<<<dim3(64, 8), 256, 0, stream>>>(xn, w16, xz);
    k_xproj<<<dim3(256), 128, 0, stream>>>(xz, w16, xdf);
    k_scan1<<<dim3(NC, 2), 512, 0, stream>>>(xz, xdf, w16, cA, cH, NC, CL);
    k_scan2<<<dim3(16, 4, 2), 128, 0, stream>>>(cA, cH, NC);
    k_scan3<<<dim3(NC, 2), 512, 0, stream>>>(xz, xdf, w16, cH, y, NC, CL);
    k_out<<<dim3(4, 64), 256, 0, stream>>>(y, w16, resnet, sp16, d_out);
}